// Round 4
// baseline (1265.872 us; speedup 1.0000x reference)
//
#include <hip/hip_runtime.h>
#include <hip/hip_fp16.h>

// Problem constants: B=64, N=256, F_IN=768, F_OUT=256
#define NB    64
#define NN    256
#define FIN   768
#define FOUT  256

typedef _Float16 half2v __attribute__((ext_vector_type(2)));
typedef _Float16 half8v __attribute__((ext_vector_type(8)));
typedef float    float4v __attribute__((ext_vector_type(4)));

__device__ inline half2v u2hv(unsigned int u){
  union { unsigned int u; half2v h; } cv; cv.u = u; return cv.h;
}
__device__ inline __half2 u2h2(unsigned int u){
  union { unsigned int u; __half2 h; } cv; cv.u = u; return cv.h;
}
__device__ inline unsigned int h22u(__half2 h){
  union { __half2 h; unsigned int u; } cv; cv.h = h; return cv.u;
}
__device__ inline unsigned int packh2f(float a, float b){
  union { __half2 h; unsigned int u; } cv;
  cv.h = __floats2half2_rn(a, b);
  return cv.u;
}
__device__ inline uint4 pack8(const float* w){
  uint4 r;
  r.x = packh2f(w[0], w[1]);
  r.y = packh2f(w[2], w[3]);
  r.z = packh2f(w[4], w[5]);
  r.w = packh2f(w[6], w[7]);
  return r;
}

// f16 pair dot with f32 accumulate (v_dot2_f32_f16)
__device__ inline float fdot2u(unsigned int x, unsigned int w, float acc){
#if __has_builtin(__builtin_amdgcn_fdot2)
  return __builtin_amdgcn_fdot2(u2hv(x), u2hv(w), acc, false);
#else
  half2v a = u2hv(x), b = u2hv(w);
  return acc + (float)a[0]*(float)b[0] + (float)a[1]*(float)b[1];
#endif
}

// Park a value in an AGPR. Rounds 1-3 showed the allocator spills/remats
// VGPR-pinned invariant loads back to L2 every iteration (3.6us/step ==
// 524KB/step at ~56B/cyc per-CU L2 port). "+a" forces an accvgpr_write in
// the prologue; uses inside the loop become accvgpr_read (1 VALU op) —
// the L2 weight stream disappears.
__device__ inline void pinA4(uint4& v){
  asm volatile("" : "+a"(v.x), "+a"(v.y), "+a"(v.z), "+a"(v.w));
}

// ---------------------------------------------------------------------------
// prep: convert weights to f16 / packed-f16-pair layouts.
//  embW16  [256][768] f16   = emb_W
//  Wcat16  [768][256] f16   = [ioux_W ; coux_W]
//  biascat [768]      f32   = [ioux_b ; coux_b]
//  iouhP4  [32][512]  uint4 : entry (kk4,o) = f16 pairs of iouh_W[o][8*kk4 .. +7]
//  couhP4  [32][256]  uint4 : entry (kk4,o) = f16 pairs of couh_W[o][8*kk4 .. +7]
// total items = 196608 + 196608 + 768 + 16384 + 8192 = 418560 = 1635 * 256
// ---------------------------------------------------------------------------
__global__ __launch_bounds__(256) void prep_kernel(
    const float* __restrict__ emb_W, const float* __restrict__ ioux_W,
    const float* __restrict__ ioux_b, const float* __restrict__ coux_W,
    const float* __restrict__ coux_b, const float* __restrict__ iouh_W,
    const float* __restrict__ couh_W,
    _Float16* __restrict__ embW16, _Float16* __restrict__ Wcat16,
    float* __restrict__ biascat, uint4* __restrict__ iouhP4,
    uint4* __restrict__ couhP4)
{
  int idx = blockIdx.x*256 + threadIdx.x;
  if (idx < 196608) { embW16[idx] = (_Float16)emb_W[idx]; return; }
  idx -= 196608;
  if (idx < 196608) {
    int o = idx >> 8, k = idx & 255;
    float v = (o < 512) ? ioux_W[o*256 + k] : coux_W[(o-512)*256 + k];
    Wcat16[idx] = (_Float16)v; return;
  }
  idx -= 196608;
  if (idx < 768) { biascat[idx] = (idx < 512) ? ioux_b[idx] : coux_b[idx-512]; return; }
  idx -= 768;
  if (idx < 16384) {
    int kk4 = idx >> 9, o = idx & 511;
    iouhP4[idx] = pack8(iouh_W + o*256 + kk4*8);
    return;
  }
  idx -= 16384;
  if (idx < 8192) {
    int kk4 = idx >> 8, o = idx & 255;
    couhP4[idx] = pack8(couh_W + o*256 + kk4*8);
    return;
  }
}

// ---------------------------------------------------------------------------
// degmask: per (b,i): row degree inverse + transposed adjacency bitmask.
//  maskw[b*256+i][q] bit jj = (adj[b][32q+jj][i] != 0)
//  dinv[b*256+i] = d!=0 ? 1/d : 0 ;  d = sum_j adj[b][i][j]
// ---------------------------------------------------------------------------
__global__ __launch_bounds__(256) void degmask_kernel(
    const float* __restrict__ adj, unsigned int* __restrict__ maskw,
    float* __restrict__ dinv)
{
  const int b = blockIdx.x, i = threadIdx.x;
  const float* ab = adj + (size_t)b*NN*NN;
  #pragma unroll
  for (int q = 0; q < 8; q++){
    unsigned int wq = 0;
    for (int jj = 0; jj < 32; jj++){
      float v = ab[(size_t)(q*32+jj)*NN + i];
      wq |= (v != 0.0f) ? (1u << jj) : 0u;
    }
    maskw[((size_t)b*NN + i)*8 + q] = wq;
  }
  float s = 0.f;
  const float4* rp = (const float4*)(ab + (size_t)i*NN);
  for (int j = 0; j < NN/4; j++){ float4 v = rp[j]; s += v.x + v.y + v.z + v.w; }
  dinv[b*NN + i] = (s != 0.f) ? 1.0f/s : 0.0f;
}

// ---------------------------------------------------------------------------
// GEMM: C[m][n] = sum_k A[m][k] * Bw[n][k]  (+bias[n]), C stored f16.
// A row-major [M][K] (f32 if AF32, else f16), Bw row-major [N][K] f16.
// block = 256 threads = 4 waves; wave computes a 16x64 tile via mfma 16x16x32.
// ---------------------------------------------------------------------------
template<int AF32>
__global__ __launch_bounds__(256) void gemm16_kernel(
    const void* __restrict__ Aq, const _Float16* __restrict__ Bw,
    _Float16* __restrict__ Cout, const float* __restrict__ bias,
    int M, int N, int K, int ldc)
{
  const int wave = threadIdx.x >> 6;
  const int lane = threadIdx.x & 63;
  const int m0 = (blockIdx.x*4 + wave)*16;
  const int n0 = blockIdx.y*64;
  const int mrow = m0 + (lane & 15);
  const int kgrp = lane >> 4;
  float4v acc[4];
  #pragma unroll
  for (int nt = 0; nt < 4; nt++) acc[nt] = (float4v){0.f,0.f,0.f,0.f};

  for (int k0 = 0; k0 < K; k0 += 32){
    const int ka = k0 + kgrp*8;
    half8v af;
    if (AF32){
      const float* A = (const float*)Aq;
      const float4* ap = (const float4*)(A + (size_t)mrow*K + ka);
      float4 a0 = ap[0], a1 = ap[1];
      af[0]=(_Float16)a0.x; af[1]=(_Float16)a0.y; af[2]=(_Float16)a0.z; af[3]=(_Float16)a0.w;
      af[4]=(_Float16)a1.x; af[5]=(_Float16)a1.y; af[6]=(_Float16)a1.z; af[7]=(_Float16)a1.w;
    } else {
      const _Float16* A = (const _Float16*)Aq;
      af = *(const half8v*)(A + (size_t)mrow*K + ka);
    }
    #pragma unroll
    for (int nt = 0; nt < 4; nt++){
      const int ncol = n0 + nt*16 + (lane & 15);
      half8v bf = *(const half8v*)(Bw + (size_t)ncol*K + ka);
      acc[nt] = __builtin_amdgcn_mfma_f32_16x16x32_f16(af, bf, acc[nt], 0, 0, 0);
    }
  }
  #pragma unroll
  for (int nt = 0; nt < 4; nt++){
    const int ncol = n0 + nt*16 + (lane & 15);
    const float bv = bias ? bias[ncol] : 0.f;
    #pragma unroll
    for (int r = 0; r < 4; r++){
      const int orow = m0 + (lane>>4)*4 + r;
      Cout[(size_t)orow*ldc + ncol] = (_Float16)(acc[nt][r] + bv);
    }
  }
}

// ---------------------------------------------------------------------------
// scan: one block per batch element b; 512 threads = 8 waves.
// Recurrent weights parked in AGPRs (pinA4): thread t holds iouh column o=t
// (32 uint4) and half of a couh column o=(t&255): kk 0..63 for t<256,
// kk 64..127 for t>=256. 192 AGPR dwords + ~60-80 arch VGPRs fits the
// 256-reg budget from amdgpu_waves_per_eu(2,2) (2 waves/SIMD).
// Agg unroll capped at 4 to keep arch-VGPR pressure low.
// ---------------------------------------------------------------------------
__global__ __launch_bounds__(512)
__attribute__((amdgpu_waves_per_eu(2, 2)))
void scan_kernel(
    _Float16* __restrict__ Hc,          // [B*N][256] f16, init = h_e
    const _Float16* __restrict__ OUTX,  // [B*N][768] f16: [iou_x ; cou_x] (+x-biases)
    const uint4* __restrict__ iouhP4,   // [32][512]
    const uint4* __restrict__ couhP4,   // [32][256]
    const float* __restrict__ dinv,     // [B*N]
    const unsigned int* __restrict__ maskw, // [B*N][8] (+1 row pad)
    const float* __restrict__ iouh_b,   // [512]
    const float* __restrict__ couh_b,   // [256]
    const float* __restrict__ fc_W,     // [2][256]
    const float* __restrict__ fc_b,     // [2]
    float* __restrict__ out)            // [B][2]
{
  const int b    = blockIdx.x;
  const int t    = threadIdx.x;
  const int wave = t >> 6;
  const int lane = t & 63;

  __shared__ __align__(16) unsigned int xph2[128]; // x_parent f16 pairs
  __shared__ float xp32[256];                      // x_parent f32
  __shared__ __align__(16) _Float16 rxp_h[256];    // r * x_parent, f16
  __shared__ __align__(16) unsigned int part[8][128]; // per-wave agg partials (f16 pairs)
  __shared__ float coup[256];                      // cou partial from t<256 half
  __shared__ float pmLDS[256];                     // pooled max

  // ---- load recurrent weights and park them in AGPRs ----
  uint4 wreg[32];
  #pragma unroll
  for (int q = 0; q < 32; q++) wreg[q] = iouhP4[q*512 + t];
  const int oc = t & 255;
  const int qb = (t < 256) ? 0 : 16;
  uint4 creg[16];
  #pragma unroll
  for (int q = 0; q < 16; q++) creg[q] = couhP4[(qb + q)*256 + oc];
  #pragma unroll
  for (int q = 0; q < 32; q++) pinA4(wreg[q]);
  #pragma unroll
  for (int q = 0; q < 16; q++) pinA4(creg[q]);

  const float biou = iouh_b[t];
  const float bcou = couh_b[oc];
  float pmax = -1e30f;
  const size_t hbase = (size_t)b * (NN*FOUT);

  // software-pipelined mask load (maskw gates the agg phase at L2 latency)
  unsigned int mcur = maskw[((size_t)b*NN)*8 + wave];

  #pragma unroll 1
  for (int i = 0; i < NN; i++){
    const size_t row = (size_t)b*NN + i;

    // prefetch next step's mask + this step's OUTX operands (used after B2/B4)
    const unsigned int mnext = maskw[(row+1)*8 + wave];
    const float oxi = (float)OUTX[row*768 + t];
    const float oxc = (float)OUTX[row*768 + 512 + oc];

    // ---- aggregation: wave handles source rows [32*wave, 32*wave+32) ----
    const unsigned int m = mcur;
    __half2 acc0 = __floats2half2_rn(0.f, 0.f);
    __half2 acc1 = acc0;
    const _Float16* hrow0 = Hc + hbase + (size_t)(wave*32)*FOUT + lane*4;
    #pragma unroll 4
    for (int jj = 0; jj < 32; jj++){
      uint2 d2 = *(const uint2*)(hrow0 + (size_t)jj*FOUT);
      unsigned int mb = ((m >> jj) & 1u) ? 0x3C003C00u : 0u;  // (1,1) or (0,0)
      __half2 mm = u2h2(mb);
      acc0 = __hfma2(u2h2(d2.x), mm, acc0);
      acc1 = __hfma2(u2h2(d2.y), mm, acc1);
    }
    *(uint2*)&part[wave][lane*2] = make_uint2(h22u(acc0), h22u(acc1));
    mcur = mnext;
    __syncthreads();                                    // B1

    if (t < 128){
      float s0 = 0.f, s1 = 0.f;
      #pragma unroll
      for (int w2 = 0; w2 < 8; w2++){
        __half2 p = u2h2(part[w2][t]);
        s0 += __low2float(p);
        s1 += __high2float(p);
      }
      const float dv = dinv[row];
      s0 *= dv; s1 *= dv;
      xp32[2*t]   = s0;
      xp32[2*t+1] = s1;
      xph2[t] = packh2f(s0, s1);
    }
    __syncthreads();                                    // B2

    // ---- iou matvec: output o = t (0..511), weights in AGPRs ----
    float acc = oxi + biou;
    #pragma unroll
    for (int q = 0; q < 32; q++){
      uint4 xv = *(const uint4*)&xph2[q*4];
      acc = fdot2u(xv.x, wreg[q].x, acc);
      acc = fdot2u(xv.y, wreg[q].y, acc);
      acc = fdot2u(xv.z, wreg[q].z, acc);
      acc = fdot2u(xv.w, wreg[q].w, acc);
    }
    const float sg = 1.f / (1.f + __expf(-acc));  // r (t<256) or z (t>=256)
    const float zval = sg;
    if (t < 256) rxp_h[t] = (_Float16)(sg * xp32[t]);
    __syncthreads();                                    // B3

    // ---- cou matvec: both halves compute half the K range for o = t&255 ----
    float ca = 0.f;
    {
      const uint4* xr = ((const uint4*)rxp_h) + qb;
      #pragma unroll
      for (int q = 0; q < 16; q++){
        uint4 xv = xr[q];
        ca = fdot2u(xv.x, creg[q].x, ca);
        ca = fdot2u(xv.y, creg[q].y, ca);
        ca = fdot2u(xv.z, creg[q].z, ca);
        ca = fdot2u(xv.w, creg[q].w, ca);
      }
    }
    if (t < 256) coup[oc] = ca;
    __syncthreads();                                    // B4

    if (t >= 256){
      const float v   = oxc + bcou + coup[oc] + ca;
      const float hcv = tanhf(v);
      const float xpv = xp32[oc];
      const float hn  = zval*xpv + (1.f - zval)*hcv;
      pmax = fmaxf(pmax, hn);
      Hc[hbase + (size_t)i*FOUT + oc] = (_Float16)hn;
    }
    __syncthreads();                                    // B5
  }

  // ---- epilogue: pooled max -> fc ----
  if (t >= 256) pmLDS[oc] = pmax;
  __syncthreads();
  if (t < 128){
    const int c = t >> 6;   // 0 or 1
    float s = 0.f;
    #pragma unroll
    for (int q = 0; q < 4; q++){
      const int f = lane + q*64;
      s += fc_W[c*256 + f] * pmLDS[f];
    }
    #pragma unroll
    for (int off = 32; off > 0; off >>= 1) s += __shfl_xor(s, off, 64);
    if (lane == 0) out[b*2 + c] = s + fc_b[c];
  }
}

// ---------------------------------------------------------------------------
extern "C" void kernel_launch(void* const* d_in, const int* in_sizes, int n_in,
                              void* d_out, int out_size, void* d_ws, size_t ws_size,
                              hipStream_t stream)
{
  (void)in_sizes; (void)n_in; (void)out_size; (void)ws_size;
  const float* h      = (const float*)d_in[0];
  const float* adj    = (const float*)d_in[1];
  const float* emb_W  = (const float*)d_in[2];
  const float* ioux_W = (const float*)d_in[3];
  const float* ioux_b = (const float*)d_in[4];
  const float* iouh_W = (const float*)d_in[5];
  const float* iouh_b = (const float*)d_in[6];
  const float* coux_W = (const float*)d_in[7];
  const float* coux_b = (const float*)d_in[8];
  const float* couh_W = (const float*)d_in[9];
  const float* couh_b = (const float*)d_in[10];
  const float* fc_W   = (const float*)d_in[11];
  const float* fc_b   = (const float*)d_in[12];
  float* out = (float*)d_out;

  // ---- carve workspace (256B aligned chunks) ----
  size_t off = 0;
  char* base = (char*)d_ws;
  auto carve = [&](size_t bytes)->char* {
    off = (off + 255) & ~(size_t)255;
    char* p = base + off;
    off += bytes;
    return p;
  };
  _Float16* embW16 = (_Float16*)carve((size_t)256*768*2);
  _Float16* Wcat16 = (_Float16*)carve((size_t)768*256*2);
  float*    biascat= (float*)  carve((size_t)768*4);
  uint4*    iouhP4 = (uint4*)  carve((size_t)32*512*16);
  uint4*    couhP4 = (uint4*)  carve((size_t)32*256*16);
  float*    dinv   = (float*)  carve((size_t)NB*NN*4);
  unsigned int* maskw = (unsigned int*)carve((size_t)NB*NN*8*4 + 64); // +pad for i+1 prefetch
  _Float16* Hc     = (_Float16*)carve((size_t)NB*NN*FOUT*2);       // h_e -> h_copy (in place)
  _Float16* OUTX   = (_Float16*)carve((size_t)NB*NN*768*2);        // [iou_x ; cou_x]

  // 1) weight conversion / packing
  prep_kernel<<<dim3(1635), dim3(256), 0, stream>>>(
      emb_W, ioux_W, ioux_b, coux_W, coux_b, iouh_W, couh_W,
      embW16, Wcat16, biascat, iouhP4, couhP4);

  // 2) degrees + adjacency column bitmasks
  degmask_kernel<<<dim3(NB), dim3(256), 0, stream>>>(adj, maskw, dinv);

  // 3) h_e = h @ emb_W^T   (A f32 on the fly -> f16 MFMA), C f16 = Hc
  gemm16_kernel<1><<<dim3(256, 4), dim3(256), 0, stream>>>(
      (const void*)h, embW16, Hc, nullptr, NB*NN, FOUT, FIN, FOUT);

  // 4) [iou_x ; cou_x] = h_e @ Wcat^T + biascat   (f16 in/out)
  gemm16_kernel<0><<<dim3(256, 12), dim3(256), 0, stream>>>(
      (const void*)Hc, Wcat16, OUTX, biascat, NB*NN, 768, FOUT, 768);

  // 5) sequential tree scan, one block per batch element
  scan_kernel<<<dim3(NB), dim3(512), 0, stream>>>(
      Hc, OUTX, iouhP4, couhP4, dinv, maskw, iouh_b, couh_b, fc_W, fc_b, out);
}

// Round 5
// 1103.715 us; speedup vs baseline: 1.1469x; 1.1469x over previous
//
#include <hip/hip_runtime.h>
#include <hip/hip_fp16.h>

// Problem constants: B=64, N=256, F_IN=768, F_OUT=256
#define NB    64
#define NN    256
#define FIN   768
#define FOUT  256

typedef _Float16 half8v __attribute__((ext_vector_type(8)));
typedef float    float4v __attribute__((ext_vector_type(4)));

__device__ inline __half2 u2h2(unsigned int u){
  union { unsigned int u; __half2 h; } cv; cv.u = u; return cv.h;
}
__device__ inline unsigned int h22u(__half2 h){
  union { __half2 h; unsigned int u; } cv; cv.h = h; return cv.u;
}

// f32 -> fp8 e4m3 (OCP, RNE) single value
__device__ inline unsigned char enc8(float v){
#if __has_builtin(__builtin_amdgcn_cvt_pk_fp8_f32)
  return (unsigned char)(__builtin_amdgcn_cvt_pk_fp8_f32(v, v, 0, false) & 0xFF);
#else
  // brute-force nearest (correct, slow; only if builtin missing)
  float best = 1e30f; unsigned char bc = 0;
  for (int c = 0; c < 256; c++){
    if ((c & 0x7F) == 0x7F) continue;            // NaN codes
    int e = (c >> 3) & 15, mnt = c & 7;
    float mag = e ? ldexpf(1.f + mnt*0.125f, e-7) : ldexpf(mnt*0.125f, -6);
    float d = (c >> 7) ? -mag : mag;
    float err = fabsf(v - d);
    if (err < best){ best = err; bc = (unsigned char)c; }
  }
  return bc;
#endif
}

__device__ inline float4v mfma_fp8(long long a, long long b, float4v c){
  return __builtin_amdgcn_mfma_f32_16x16x32_fp8_fp8(a, b, c, 0, 0, 0);
}

// Swizzled fp8 weight layout for MFMA A-frags:
// off(o,k) = ((o>>4)*8 + (k>>5))*512 + ((k>>3)&3)*128 + (o&15)*8 + (k&7)
// so a wave's A-frag read (lane q=lane>>4, r=lane&15) is contiguous per quad.

// ---------------------------------------------------------------------------
// prep: f16 conversions for the big x-side GEMMs.
//  embW16  [256][768] f16 = emb_W
//  Wcat16  [768][256] f16 = [ioux_W ; coux_W]
//  biascat [768]      f32 = [ioux_b ; coux_b]
// items = 196608 + 196608 + 768 = 393984 = 1539*256
// ---------------------------------------------------------------------------
__global__ __launch_bounds__(256) void prep_kernel(
    const float* __restrict__ emb_W, const float* __restrict__ ioux_W,
    const float* __restrict__ ioux_b, const float* __restrict__ coux_W,
    const float* __restrict__ coux_b,
    _Float16* __restrict__ embW16, _Float16* __restrict__ Wcat16,
    float* __restrict__ biascat)
{
  int idx = blockIdx.x*256 + threadIdx.x;
  if (idx < 196608) { embW16[idx] = (_Float16)emb_W[idx]; return; }
  idx -= 196608;
  if (idx < 196608) {
    int o = idx >> 8, k = idx & 255;
    float v = (o < 512) ? ioux_W[o*256 + k] : coux_W[(o-512)*256 + k];
    Wcat16[idx] = (_Float16)v; return;
  }
  idx -= 196608;
  if (idx < 768) { biascat[idx] = (idx < 512) ? ioux_b[idx] : coux_b[idx-512]; return; }
}

// ---------------------------------------------------------------------------
// quant: per-output-row fp8 e4m3 quantization of iouh_W (rows 0..511) and
// couh_W (rows 512..767), written in the MFMA swizzled layout.
// invrs[o] = 1/(rowscale*16): undoes row scale AND the x-side scale (16).
// ---------------------------------------------------------------------------
__global__ __launch_bounds__(256) void quant_kernel(
    const float* __restrict__ iouh_W, const float* __restrict__ couh_W,
    unsigned char* __restrict__ iouh8, unsigned char* __restrict__ couh8,
    float* __restrict__ invrs_iou, float* __restrict__ invrs_cou)
{
  const int row = blockIdx.x;       // 0..767
  const int t   = threadIdx.x;      // 0..255 (k index)
  const bool is_iou = (row < 512);
  const int rl = is_iou ? row : row - 512;
  const float w = is_iou ? iouh_W[(size_t)rl*256 + t] : couh_W[(size_t)rl*256 + t];

  __shared__ float sm[256];
  sm[t] = fabsf(w);
  __syncthreads();
  for (int s = 128; s > 0; s >>= 1){
    if (t < s) sm[t] = fmaxf(sm[t], sm[t+s]);
    __syncthreads();
  }
  const float mx = sm[0];
  const float rs = (mx > 1e-20f) ? (240.0f / mx) : 1.0f;
  const unsigned char byte = enc8(w * rs);
  const int off = ((rl>>4)*8 + (t>>5))*512 + ((t>>3)&3)*128 + (rl&15)*8 + (t&7);
  if (is_iou) iouh8[off] = byte; else couh8[off] = byte;
  if (t == 0){
    const float inv = 1.0f / (rs * 16.0f);
    if (is_iou) invrs_iou[rl] = inv; else invrs_cou[rl] = inv;
  }
}

// ---------------------------------------------------------------------------
// degmask: per (b,i): row degree inverse + transposed adjacency bitmask.
// ---------------------------------------------------------------------------
__global__ __launch_bounds__(256) void degmask_kernel(
    const float* __restrict__ adj, unsigned int* __restrict__ maskw,
    float* __restrict__ dinv)
{
  const int b = blockIdx.x, i = threadIdx.x;
  const float* ab = adj + (size_t)b*NN*NN;
  #pragma unroll
  for (int q = 0; q < 8; q++){
    unsigned int wq = 0;
    for (int jj = 0; jj < 32; jj++){
      float v = ab[(size_t)(q*32+jj)*NN + i];
      wq |= (v != 0.0f) ? (1u << jj) : 0u;
    }
    maskw[((size_t)b*NN + i)*8 + q] = wq;
  }
  float s = 0.f;
  const float4* rp = (const float4*)(ab + (size_t)i*NN);
  for (int j = 0; j < NN/4; j++){ float4 v = rp[j]; s += v.x + v.y + v.z + v.w; }
  dinv[b*NN + i] = (s != 0.f) ? 1.0f/s : 0.0f;
}

// ---------------------------------------------------------------------------
// GEMM (unchanged, validated): C = A @ Bw^T (+bias), C f16.
// ---------------------------------------------------------------------------
template<int AF32>
__global__ __launch_bounds__(256) void gemm16_kernel(
    const void* __restrict__ Aq, const _Float16* __restrict__ Bw,
    _Float16* __restrict__ Cout, const float* __restrict__ bias,
    int M, int N, int K, int ldc)
{
  const int wave = threadIdx.x >> 6;
  const int lane = threadIdx.x & 63;
  const int m0 = (blockIdx.x*4 + wave)*16;
  const int n0 = blockIdx.y*64;
  const int mrow = m0 + (lane & 15);
  const int kgrp = lane >> 4;
  float4v acc[4];
  #pragma unroll
  for (int nt = 0; nt < 4; nt++) acc[nt] = (float4v){0.f,0.f,0.f,0.f};

  for (int k0 = 0; k0 < K; k0 += 32){
    const int ka = k0 + kgrp*8;
    half8v af;
    if (AF32){
      const float* A = (const float*)Aq;
      const float4* ap = (const float4*)(A + (size_t)mrow*K + ka);
      float4 a0 = ap[0], a1 = ap[1];
      af[0]=(_Float16)a0.x; af[1]=(_Float16)a0.y; af[2]=(_Float16)a0.z; af[3]=(_Float16)a0.w;
      af[4]=(_Float16)a1.x; af[5]=(_Float16)a1.y; af[6]=(_Float16)a1.z; af[7]=(_Float16)a1.w;
    } else {
      const _Float16* A = (const _Float16*)Aq;
      af = *(const half8v*)(A + (size_t)mrow*K + ka);
    }
    #pragma unroll
    for (int nt = 0; nt < 4; nt++){
      const int ncol = n0 + nt*16 + (lane & 15);
      half8v bf = *(const half8v*)(Bw + (size_t)ncol*K + ka);
      acc[nt] = __builtin_amdgcn_mfma_f32_16x16x32_f16(af, bf, acc[nt], 0, 0, 0);
    }
  }
  #pragma unroll
  for (int nt = 0; nt < 4; nt++){
    const int ncol = n0 + nt*16 + (lane & 15);
    const float bv = bias ? bias[ncol] : 0.f;
    #pragma unroll
    for (int r = 0; r < 4; r++){
      const int orow = m0 + (lane>>4)*4 + r;
      Cout[(size_t)orow*ldc + ncol] = (_Float16)(acc[nt][r] + bv);
    }
  }
}

// ---------------------------------------------------------------------------
// scan: one block per batch element; 512 threads = 8 waves.
// iouh fp8 resident in LDS (128KB), consumed by mfma fp8 matvec (B = xp fp8,
// all 16 B-columns identical -> any D column is the matvec).
// couh fp8 streamed per step as MFMA A-frags (64KB/step, prefetched).
// Agg: wave-uniform mask skip with loads hoisted for MLP.
// LDS map (dynamic, 140800 B):
//   [0)       iouh8 swizzled   131072
//   [131072)  part (8x128 u32)   4096
//   [135168)  xp32 (256 f32)     1024
//   [136192)  xp8  (256 B)        256
//   [136448)  p8   (256 B)        256
//   [136704)  ioud (512 f32)     2048
//   [138752)  coud (256 f32)     1024
//   [139776)  pm   (256 f32)     1024
// ---------------------------------------------------------------------------
#define SCAN_LDS 140800

__global__ __launch_bounds__(512, 2)
void scan_kernel(
    _Float16* __restrict__ Hc,          // [B*N][256] f16, init = h_e
    const _Float16* __restrict__ OUTX,  // [B*N][768] f16: [iou_x ; cou_x]
    const unsigned char* __restrict__ iouh8,  // swizzled fp8 [512][256]
    const unsigned char* __restrict__ couh8,  // swizzled fp8 [256][256]
    const float* __restrict__ invrs_iou,      // [512]
    const float* __restrict__ invrs_cou,      // [256]
    const float* __restrict__ dinv,     // [B*N]
    const unsigned int* __restrict__ maskw, // [B*N][8] (+pad)
    const float* __restrict__ iouh_b,   // [512]
    const float* __restrict__ couh_b,   // [256]
    const float* __restrict__ fc_W,     // [2][256]
    const float* __restrict__ fc_b,     // [2]
    float* __restrict__ out)            // [B][2]
{
  const int b    = blockIdx.x;
  const int t    = threadIdx.x;
  const int wave = t >> 6;
  const int lane = t & 63;
  const int q    = lane >> 4;    // k-octet within MFMA frags
  const int r    = lane & 15;    // row within MFMA tile

  extern __shared__ __align__(16) char smem[];
  unsigned char* sh_w    = (unsigned char*)smem;
  unsigned int*  sh_part = (unsigned int*)(smem + 131072);
  float*         sh_xp32 = (float*)(smem + 135168);
  unsigned char* sh_xp8  = (unsigned char*)(smem + 136192);
  unsigned char* sh_p8   = (unsigned char*)(smem + 136448);
  float*         sh_ioud = (float*)(smem + 136704);
  float*         sh_coud = (float*)(smem + 138752);
  float*         sh_pm   = (float*)(smem + 139776);

  // ---- stage iouh fp8 into LDS (once): 131072 B = 8192 uint4 ----
  {
    const uint4* src = (const uint4*)iouh8;
    uint4* dst = (uint4*)sh_w;
    #pragma unroll
    for (int qq = 0; qq < 16; qq++) dst[qq*512 + t] = src[qq*512 + t];
  }
  __syncthreads();

  const int oc   = t & 255;
  const float biou = iouh_b[t];
  const float bcou = couh_b[oc];
  const float invi = invrs_iou[t];
  const float invc = invrs_cou[oc];
  float pmax = -1e30f;
  const size_t hbase = (size_t)b * (NN*FOUT);
  const _Float16* hrow0 = Hc + hbase + (size_t)(wave*32)*FOUT + lane*4;

  unsigned int mcur = maskw[((size_t)b*NN)*8 + wave];

  #pragma unroll 1
  for (int i = 0; i < NN; i++){
    const size_t row = (size_t)b*NN + i;

    // ---- prefetch couh A-frags for this step (invariant addresses) ----
    long long cfrag[2][8];
    #pragma unroll
    for (int tt = 0; tt < 2; tt++)
      #pragma unroll
      for (int kc = 0; kc < 8; kc++)
        cfrag[tt][kc] = *(const long long*)(couh8 + ((wave*2+tt)*8 + kc)*512 + q*128 + r*8);

    const unsigned int mnext = maskw[(row+1)*8 + wave];
    const float oxi = (float)OUTX[row*768 + t];
    const float oxc = (float)OUTX[row*768 + 512 + oc];

    // ---- aggregation with wave-uniform mask skip ----
    const unsigned int m = (unsigned int)__builtin_amdgcn_readfirstlane((int)mcur);
    uint2 dbuf[32];
    #pragma unroll
    for (int jj = 0; jj < 32; jj++){
      if ((m >> jj) & 1u) dbuf[jj] = *(const uint2*)(hrow0 + (size_t)jj*FOUT);
    }
    __half2 a0 = __floats2half2_rn(0.f, 0.f), a1 = a0;
    #pragma unroll
    for (int jj = 0; jj < 32; jj++){
      if ((m >> jj) & 1u){
        a0 = __hadd2(a0, u2h2(dbuf[jj].x));
        a1 = __hadd2(a1, u2h2(dbuf[jj].y));
      }
    }
    sh_part[wave*128 + lane*2]     = h22u(a0);
    sh_part[wave*128 + lane*2 + 1] = h22u(a1);
    mcur = mnext;
    __syncthreads();                                    // B1

    // ---- reduce partials -> x_parent (f32 + fp8*16) ----
    if (t < 128){
      float s0 = 0.f, s1 = 0.f;
      #pragma unroll
      for (int w2 = 0; w2 < 8; w2++){
        __half2 p = u2h2(sh_part[w2*128 + t]);
        s0 += __low2float(p);
        s1 += __high2float(p);
      }
      const float dv = dinv[row];
      s0 *= dv; s1 *= dv;
      sh_xp32[2*t]   = s0;
      sh_xp32[2*t+1] = s1;
      const unsigned short us =
          (unsigned short)enc8(s0 * 16.f) |
          ((unsigned short)enc8(s1 * 16.f) << 8);
      ((unsigned short*)sh_xp8)[t] = us;
    }
    __syncthreads();                                    // B2

    // ---- iou matvec via fp8 MFMA: 4 tiles of 16 outputs per wave ----
    {
      float4v iacc[4];
      #pragma unroll
      for (int tt = 0; tt < 4; tt++) iacc[tt] = (float4v){0.f,0.f,0.f,0.f};
      #pragma unroll
      for (int kc = 0; kc < 8; kc++){
        const long long bfr = *(const long long*)(sh_xp8 + kc*32 + q*8);
        #pragma unroll
        for (int tt = 0; tt < 4; tt++){
          const long long afr = *(const long long*)(sh_w + ((wave*4+tt)*8 + kc)*512 + q*128 + r*8);
          iacc[tt] = mfma_fp8(afr, bfr, iacc[tt]);
        }
      }
      if (r == 0){
        #pragma unroll
        for (int tt = 0; tt < 4; tt++)
          #pragma unroll
          for (int r4 = 0; r4 < 4; r4++)
            sh_ioud[(wave*4+tt)*16 + q*4 + r4] = iacc[tt][r4];
      }
    }
    __syncthreads();                                    // B3

    // ---- gates ----
    const float iouv = sh_ioud[t]*invi + oxi + biou;
    const float sg = 1.f / (1.f + __expf(-iouv));       // r (t<256) / z (t>=256)
    const float zval = sg;
    if (t < 256) sh_p8[t] = enc8(sg * sh_xp32[t] * 16.f);
    __syncthreads();                                    // B4

    // ---- cou matvec via fp8 MFMA: 2 tiles per wave ----
    {
      float4v cacc[2];
      #pragma unroll
      for (int tt = 0; tt < 2; tt++) cacc[tt] = (float4v){0.f,0.f,0.f,0.f};
      #pragma unroll
      for (int kc = 0; kc < 8; kc++){
        const long long bfr = *(const long long*)(sh_p8 + kc*32 + q*8);
        #pragma unroll
        for (int tt = 0; tt < 2; tt++)
          cacc[tt] = mfma_fp8(cfrag[tt][kc], bfr, cacc[tt]);
      }
      if (r == 0){
        #pragma unroll
        for (int tt = 0; tt < 2; tt++)
          #pragma unroll
          for (int r4 = 0; r4 < 4; r4++)
            sh_coud[(wave*2+tt)*16 + q*4 + r4] = cacc[tt][r4];
      }
    }
    __syncthreads();                                    // B5

    // ---- update ----
    if (t >= 256){
      const float v   = sh_coud[oc]*invc + oxc + bcou;
      const float hcv = tanhf(v);
      const float xpv = sh_xp32[oc];
      const float hn  = zval*xpv + (1.f - zval)*hcv;
      pmax = fmaxf(pmax, hn);
      Hc[hbase + (size_t)i*FOUT + oc] = (_Float16)hn;
    }
    __syncthreads();                                    // B6
  }

  // ---- epilogue: pooled max -> fc ----
  if (t >= 256) sh_pm[oc] = pmax;
  __syncthreads();
  if (t < 128){
    const int c = t >> 6;   // 0 or 1
    float s = 0.f;
    #pragma unroll
    for (int qq = 0; qq < 4; qq++){
      const int f = lane + qq*64;
      s += fc_W[c*256 + f] * sh_pm[f];
    }
    #pragma unroll
    for (int off = 32; off > 0; off >>= 1) s += __shfl_xor(s, off, 64);
    if (lane == 0) out[b*2 + c] = s + fc_b[c];
  }
}

// ---------------------------------------------------------------------------
extern "C" void kernel_launch(void* const* d_in, const int* in_sizes, int n_in,
                              void* d_out, int out_size, void* d_ws, size_t ws_size,
                              hipStream_t stream)
{
  (void)in_sizes; (void)n_in; (void)out_size; (void)ws_size;
  const float* h      = (const float*)d_in[0];
  const float* adj    = (const float*)d_in[1];
  const float* emb_W  = (const float*)d_in[2];
  const float* ioux_W = (const float*)d_in[3];
  const float* ioux_b = (const float*)d_in[4];
  const float* iouh_W = (const float*)d_in[5];
  const float* iouh_b = (const float*)d_in[6];
  const float* coux_W = (const float*)d_in[7];
  const float* coux_b = (const float*)d_in[8];
  const float* couh_W = (const float*)d_in[9];
  const float* couh_b = (const float*)d_in[10];
  const float* fc_W   = (const float*)d_in[11];
  const float* fc_b   = (const float*)d_in[12];
  float* out = (float*)d_out;

  // ---- carve workspace (256B aligned chunks) ----
  size_t off = 0;
  char* base = (char*)d_ws;
  auto carve = [&](size_t bytes)->char* {
    off = (off + 255) & ~(size_t)255;
    char* p = base + off;
    off += bytes;
    return p;
  };
  _Float16* embW16 = (_Float16*)carve((size_t)256*768*2);
  _Float16* Wcat16 = (_Float16*)carve((size_t)768*256*2);
  float*    biascat= (float*)  carve((size_t)768*4);
  unsigned char* iouh8 = (unsigned char*)carve(131072);
  unsigned char* couh8 = (unsigned char*)carve(65536);
  float*    invrs_iou = (float*)carve(512*4);
  float*    invrs_cou = (float*)carve(256*4);
  float*    dinv   = (float*)  carve((size_t)NB*NN*4);
  unsigned int* maskw = (unsigned int*)carve((size_t)NB*NN*8*4 + 64); // +pad for prefetch
  _Float16* Hc     = (_Float16*)carve((size_t)NB*NN*FOUT*2);       // h_e -> h_copy
  _Float16* OUTX   = (_Float16*)carve((size_t)NB*NN*768*2);        // [iou_x ; cou_x]

  // raise dynamic LDS cap for the scan kernel (idempotent, non-stream op)
  hipFuncSetAttribute((const void*)scan_kernel,
                      hipFuncAttributeMaxDynamicSharedMemorySize, SCAN_LDS);

  // 1) f16 weight conversion for x-side GEMMs
  prep_kernel<<<dim3(1539), dim3(256), 0, stream>>>(
      emb_W, ioux_W, ioux_b, coux_W, coux_b, embW16, Wcat16, biascat);

  // 2) fp8 quantization of recurrent weights (swizzled for MFMA frags)
  quant_kernel<<<dim3(768), dim3(256), 0, stream>>>(
      iouh_W, couh_W, iouh8, couh8, invrs_iou, invrs_cou);

  // 3) degrees + adjacency column bitmasks
  degmask_kernel<<<dim3(NB), dim3(256), 0, stream>>>(adj, maskw, dinv);

  // 4) h_e = h @ emb_W^T
  gemm16_kernel<1><<<dim3(256, 4), dim3(256), 0, stream>>>(
      (const void*)h, embW16, Hc, nullptr, NB*NN, FOUT, FIN, FOUT);

  // 5) [iou_x ; cou_x] = h_e @ Wcat^T + biascat
  gemm16_kernel<0><<<dim3(256, 12), dim3(256), 0, stream>>>(
      (const void*)Hc, Wcat16, OUTX, biascat, NB*NN, 768, FOUT, 768);

  // 6) sequential tree scan
  scan_kernel<<<dim3(NB), dim3(512), SCAN_LDS, stream>>>(
      Hc, OUTX, iouh8, couh8, invrs_iou, invrs_cou, dinv, maskw,
      iouh_b, couh_b, fc_W, fc_b, out);
}